// Round 9
// baseline (328.475 us; speedup 1.0000x reference)
//
#include <hip/hip_runtime.h>

// CRF NLL, round 9: exp-space forward recursion, one wave per batch.
// Change vs r7 (single variable): the 64-value broadcast of E uses
// ds_bpermute_b32 (DS pipe, VGPR destination) instead of v_readlane
// (VALU, SGPR destination). R4/R6/R7 proved readlane's ~9cyc/pair cost is
// invariant under pipelining (slow transposed-RF issue); bpermute issues on
// the DS pipe which overlaps the VALU fmac stream, and broadcast is its
// conflict-free case. Addresses: one opaque zero VGPR + 4*i folded into the
// DS offset immediate.
#define BB 512
#define SS 512
#define TT 64
#define START_TAG 62
#define STOP_TAG 63

#define LOG2E 1.4426950408889634f
#define LN2   0.6931471805599453f

__device__ __forceinline__ float bcast0(float x) {
    return __int_as_float(__builtin_amdgcn_readfirstlane(__float_as_int(x)));
}
// broadcast E from lane i to all lanes via ds_bpermute (addr = zb + 4*i)
__device__ __forceinline__ float bperm(int zb, int i, float x) {
    return __int_as_float(
        __builtin_amdgcn_ds_bpermute(zb + 4 * i, __float_as_int(x)));
}

// D[to=lane] = sum_from E[from] * vt[from]; bpermute broadcasts pipelined
// one group of 8 ahead of their fmac consumers. All indices constant.
__device__ __forceinline__ float matvec64(const int zb, const float E,
                                          const float (&vt)[64]) {
    float a0 = 0.f, a1 = 0.f, a2 = 0.f, a3 = 0.f;
    float t[2][8];
    #pragma unroll
    for (int j = 0; j < 8; ++j) t[0][j] = bperm(zb, j, E);
    #pragma unroll
    for (int g = 0; g < 8; ++g) {
        const int cur = g & 1, nxt = cur ^ 1;
        if (g < 7) {
            #pragma unroll
            for (int j = 0; j < 8; ++j) t[nxt][j] = bperm(zb, 8 * g + 8 + j, E);
        }
        a0 = fmaf(t[cur][0], vt[8 * g + 0], a0);
        a1 = fmaf(t[cur][1], vt[8 * g + 1], a1);
        a2 = fmaf(t[cur][2], vt[8 * g + 2], a2);
        a3 = fmaf(t[cur][3], vt[8 * g + 3], a3);
        a0 = fmaf(t[cur][4], vt[8 * g + 4], a0);
        a1 = fmaf(t[cur][5], vt[8 * g + 5], a1);
        a2 = fmaf(t[cur][6], vt[8 * g + 6], a2);
        a3 = fmaf(t[cur][7], vt[8 * g + 7], a3);
    }
    return (a0 + a1) + (a2 + a3);
}

__global__ void __launch_bounds__(128)
__attribute__((amdgpu_waves_per_eu(1, 1))) crf_main(
    const float* __restrict__ feats, const int* __restrict__ mask,
    const int* __restrict__ tags, const float* __restrict__ trans,
    float* __restrict__ out)
{
    const int b    = blockIdx.x;
    const int tid  = threadIdx.x;
    const int lane = tid & 63;

    const float* frow = feats + (size_t)b * SS * TT;
    const int*   mrow = mask + b * SS;

    if (tid < 64) {
        // ---------------- forward (log partition), one wave per batch --------
        int cnt = 0;
        #pragma unroll
        for (int s = lane; s < SS; s += 64) cnt += (mrow[s] != 0);
        #pragma unroll
        for (int off = 32; off; off >>= 1) cnt += __shfl_xor(cnt, off);
        const int len = cnt;                       // in [SS/2, SS]

        // opaque zero base for bpermute addresses (loop-invariant VGPR)
        int zb;
        asm volatile("v_mov_b32 %0, 0" : "=v"(zb));

        // M[from=i][to=lane] in exp2 space (constant across the scan)
        float vt[64];
        #pragma unroll
        for (int i = 0; i < 64; ++i)
            vt[i] = __builtin_amdgcn_exp2f(trans[i * TT + lane] * LOG2E);

        // init: P0[to] = f[0,to] + trans[START,to];  E = exp2((P0-offs)*log2e)
        const float P0   = frow[lane] + trans[START_TAG * TT + lane];
        const float offs = bcast0(P0);
        float E = __builtin_amdgcn_exp2f((P0 - offs) * LOG2E);
        int ksum = 0;

        // 8-deep feats row ring (1 VGPR per row), rows s..s+7 for s=1
        float fr[8];
        #pragma unroll
        for (int j = 0; j < 8; ++j) {
            int r = 1 + j; if (r > SS - 1) r = SS - 1;
            fr[j] = frow[(size_t)r * TT + lane];
        }

        int s = 1;
        for (; s + 3 < len; s += 4) {
            // issue next block's loads (rows s+8..s+11); consumed 8 steps later
            float n0, n1, n2, n3;
            {
                int r0 = s + 8, r1 = s + 9, r2 = s + 10, r3 = s + 11;
                if (r0 > SS - 1) r0 = SS - 1;
                if (r1 > SS - 1) r1 = SS - 1;
                if (r2 > SS - 1) r2 = SS - 1;
                if (r3 > SS - 1) r3 = SS - 1;
                n0 = frow[(size_t)r0 * TT + lane];
                n1 = frow[(size_t)r1 * TT + lane];
                n2 = frow[(size_t)r2 * TT + lane];
                n3 = frow[(size_t)r3 * TT + lane];
            }

            // 3 plain steps (no rescale; growth bounded < 2^16/step)
            #pragma unroll
            for (int j = 0; j < 3; ++j) {
                const float fe = __builtin_amdgcn_exp2f(fr[j] * LOG2E);
                const float D  = matvec64(zb, E, vt);
                E = fe * D;
            }
            // 4th step with exact pow2 rescale
            {
                const float fe = __builtin_amdgcn_exp2f(fr[3] * LOG2E);
                const float D  = matvec64(zb, E, vt);
                const int ebits = (__builtin_amdgcn_readfirstlane(
                                       __float_as_int(D)) >> 23) & 0xff;
                ksum += ebits - 127;
                const float scale = __int_as_float((254 - ebits) << 23);
                E = fe * (D * scale);
            }

            // ring shift, constant indices -> pure register renaming
            #pragma unroll
            for (int j = 0; j < 4; ++j) fr[j] = fr[j + 4];
            fr[4] = n0; fr[5] = n1; fr[6] = n2; fr[7] = n3;
        }

        // tail: up to 3 steps, constant-index guarded (no dynamic fr[j])
        const int rem = len - s;   // 0..3
        #pragma unroll
        for (int j = 0; j < 3; ++j) {
            if (j < rem) {
                const float fe = __builtin_amdgcn_exp2f(fr[j] * LOG2E);
                const float D  = matvec64(zb, E, vt);
                const int ebits = (__builtin_amdgcn_readfirstlane(
                                       __float_as_int(D)) >> 23) & 0xff;
                ksum += ebits - 127;
                const float scale = __int_as_float((254 - ebits) << 23);
                E = fe * (D * scale);
            }
        }

        // final transition to STOP: lse_from(P[from] + trans[from,STOP])
        const float ts = __builtin_amdgcn_exp2f(trans[lane * TT + STOP_TAG] * LOG2E);
        float e = E * ts;
        #pragma unroll
        for (int off = 32; off; off >>= 1) e += __shfl_xor(e, off);

        if (lane == 0)
            atomicAdd(out, offs + (float)ksum * LN2
                           + LN2 * __builtin_amdgcn_logf(e));
    } else {
        // ---------------- gold score, wave 1 of the block --------------------
        const int* trow = tags + b * SS;
        int   cnt = 0;
        float acc = 0.f;
        for (int s = lane; s < SS; s += 64) {
            if (mrow[s] != 0) {
                ++cnt;
                const int tag  = trow[s];
                const int prev = (s == 0) ? START_TAG : trow[s - 1];
                acc += frow[(size_t)s * TT + tag] + trans[prev * TT + tag];
            }
        }
        #pragma unroll
        for (int off = 32; off; off >>= 1) {
            acc += __shfl_xor(acc, off);
            cnt += __shfl_xor(cnt, off);
        }
        if (lane == 0) {
            const int end_id = trow[cnt - 1];
            atomicAdd(out, -(acc + trans[end_id * TT + STOP_TAG]));
        }
    }
}

__global__ void zero_out(float* out) { out[0] = 0.f; }

extern "C" void kernel_launch(void* const* d_in, const int* in_sizes, int n_in,
                              void* d_out, int out_size, void* d_ws, size_t ws_size,
                              hipStream_t stream) {
    const float* feats = (const float*)d_in[0];   // (B,S,T) f32
    const int*   mask  = (const int*)d_in[1];     // (B,S)   int (0/1)
    const int*   tags  = (const int*)d_in[2];     // (B,S)   int
    const float* trans = (const float*)d_in[3];   // (T,T)   f32
    float* out = (float*)d_out;

    zero_out<<<1, 1, 0, stream>>>(out);
    crf_main<<<BB, 128, 0, stream>>>(feats, mask, tags, trans, out);
}

// Round 11
// 174.768 us; speedup vs baseline: 1.8795x; 1.8795x over previous
//
#include <hip/hip_runtime.h>

// CRF NLL, round 11: exp-space forward recursion, one wave per batch.
// = R10 (uniform-address ds_read_b128 broadcast of E from LDS, 8 fp16/read;
//   packed fdot2, 32 MAC-instrs/step) with the NaN fixed:
// R10 stored E with a STALE pow2 rescale -> stored magnitude up to 2^16*fe,
// which overflows fp16 (65504) -> inf -> NaN. bf16-R8 survived only via f32
// range. Fix: apply the exact rescale IN the same step; then stored
// E = fe*(D*scale) with D*scale in [0.5,4] -> |E| <= ~1e3, fp16-safe.
#define BB 512
#define SS 512
#define TT 64
#define START_TAG 62
#define STOP_TAG 63

#define LOG2E 1.4426950408889634f
#define LN2   0.6931471805599453f

typedef _Float16 h2 __attribute__((ext_vector_type(2)));
typedef _Float16 h8 __attribute__((ext_vector_type(8)));

__device__ __forceinline__ float bcast0(float x) {
    return __int_as_float(__builtin_amdgcn_readfirstlane(__float_as_int(x)));
}

// D[to=lane] = sum_from E[from] * M[from][lane]; E broadcast from LDS via
// 8 uniform-address b128 reads (8 fp16 each), 32 packed dot2, 8 accumulators.
__device__ __forceinline__ float matvec_dot(const _Float16* Ebuf,
                                            const h2 (&Mh)[32]) {
    float a0 = 0.f, a1 = 0.f, a2 = 0.f, a3 = 0.f;
    float a4 = 0.f, a5 = 0.f, a6 = 0.f, a7 = 0.f;
    h8 v[8];
    #pragma unroll
    for (int j = 0; j < 8; ++j) v[j] = *(const h8*)(Ebuf + 8 * j);
    #pragma unroll
    for (int j = 0; j < 8; ++j) {
        const h2 p0 = __builtin_shufflevector(v[j], v[j], 0, 1);
        const h2 p1 = __builtin_shufflevector(v[j], v[j], 2, 3);
        const h2 p2 = __builtin_shufflevector(v[j], v[j], 4, 5);
        const h2 p3 = __builtin_shufflevector(v[j], v[j], 6, 7);
        a0 = __builtin_amdgcn_fdot2(p0, Mh[4 * j + 0], a0, false);
        a1 = __builtin_amdgcn_fdot2(p1, Mh[4 * j + 1], a1, false);
        a2 = __builtin_amdgcn_fdot2(p2, Mh[4 * j + 2], a2, false);
        a3 = __builtin_amdgcn_fdot2(p3, Mh[4 * j + 3], a3, false);
        // rotate accumulator banks to keep chains 4-deep
        const float t = a0; a0 = a4; a4 = t;
        const float u = a1; a1 = a5; a5 = u;
        const float w = a2; a2 = a6; a6 = w;
        const float x = a3; a3 = a7; a7 = x;
    }
    return ((a0 + a1) + (a2 + a3)) + ((a4 + a5) + (a6 + a7));
}

// one scan step; EXACT pow2 rescale applied in the same step (fp16 range)
#define STEP(FRJ) { \
    const float fe = __builtin_amdgcn_exp2f((FRJ) * LOG2E); \
    const float D  = matvec_dot(Ebuf, Mh); \
    const int eb = (__builtin_amdgcn_readfirstlane(__float_as_int(D)) \
                    >> 23) & 0xff; \
    ksum += eb - 127; \
    const float scale = __int_as_float((254 - eb) << 23); \
    Ebuf[lane] = (_Float16)(fe * (D * scale)); \
}

__global__ void __launch_bounds__(128)
__attribute__((amdgpu_waves_per_eu(1, 1))) crf_main(
    const float* __restrict__ feats, const int* __restrict__ mask,
    const int* __restrict__ tags, const float* __restrict__ trans,
    float* __restrict__ out)
{
    const int b    = blockIdx.x;
    const int tid  = threadIdx.x;
    const int lane = tid & 63;

    const float* frow = feats + (size_t)b * SS * TT;
    const int*   mrow = mask + b * SS;

    __shared__ __align__(16) _Float16 Ebuf[TT];

    if (tid < 64) {
        // ---------------- forward (log partition), one wave per batch --------
        int cnt = 0;
        #pragma unroll
        for (int s = lane; s < SS; s += 64) cnt += (mrow[s] != 0);
        #pragma unroll
        for (int off = 32; off; off >>= 1) cnt += __shfl_xor(cnt, off);
        const int len = cnt;                       // in [SS/2, SS]

        // M[from][to=lane] = exp2(trans*log2e), fp16 pairs over 'from'
        h2 Mh[32];
        #pragma unroll
        for (int p = 0; p < 32; ++p) {
            const float m0 =
                __builtin_amdgcn_exp2f(trans[(2 * p) * TT + lane] * LOG2E);
            const float m1 =
                __builtin_amdgcn_exp2f(trans[(2 * p + 1) * TT + lane] * LOG2E);
            Mh[p][0] = (_Float16)m0;
            Mh[p][1] = (_Float16)m1;
        }

        // init: P0[to] = f[0,to] + trans[START,to];  E = e^(P0-offs)
        const float P0   = frow[lane] + trans[START_TAG * TT + lane];
        const float offs = bcast0(P0);
        Ebuf[lane] = (_Float16)__builtin_amdgcn_exp2f((P0 - offs) * LOG2E);
        int ksum = 0;

        // 8-deep feats row ring (1 VGPR per row), rows s..s+7 for s=1
        float fr[8];
        #pragma unroll
        for (int j = 0; j < 8; ++j) {
            int r = 1 + j; if (r > SS - 1) r = SS - 1;
            fr[j] = frow[(size_t)r * TT + lane];
        }

        int s = 1;
        for (; s + 3 < len; s += 4) {
            // issue next block's loads (rows s+8..s+11); consumed 8 steps later
            float n0, n1, n2, n3;
            {
                int r0 = s + 8, r1 = s + 9, r2 = s + 10, r3 = s + 11;
                if (r0 > SS - 1) r0 = SS - 1;
                if (r1 > SS - 1) r1 = SS - 1;
                if (r2 > SS - 1) r2 = SS - 1;
                if (r3 > SS - 1) r3 = SS - 1;
                n0 = frow[(size_t)r0 * TT + lane];
                n1 = frow[(size_t)r1 * TT + lane];
                n2 = frow[(size_t)r2 * TT + lane];
                n3 = frow[(size_t)r3 * TT + lane];
            }

            STEP(fr[0]) STEP(fr[1]) STEP(fr[2]) STEP(fr[3])

            // ring shift, constant indices -> pure register renaming
            #pragma unroll
            for (int j = 0; j < 4; ++j) fr[j] = fr[j + 4];
            fr[4] = n0; fr[5] = n1; fr[6] = n2; fr[7] = n3;
        }

        // tail: up to 3 steps, constant-index guarded
        const int rem = len - s;   // 0..3
        if (rem > 0) { STEP(fr[0]) }
        if (rem > 1) { STEP(fr[1]) }
        if (rem > 2) { STEP(fr[2]) }

        // final transition to STOP: lse_from(E[from] * M[from,STOP])
        const float Ev = (float)Ebuf[lane];
        const float Ms =
            __builtin_amdgcn_exp2f(trans[lane * TT + STOP_TAG] * LOG2E);
        float e = Ev * Ms;
        #pragma unroll
        for (int off = 32; off; off >>= 1) e += __shfl_xor(e, off);

        if (lane == 0)
            atomicAdd(out, offs + (float)ksum * LN2
                           + LN2 * __builtin_amdgcn_logf(e));
    } else {
        // ---------------- gold score, wave 1 of the block --------------------
        const int* trow = tags + b * SS;
        int   cnt = 0;
        float acc = 0.f;
        for (int s = lane; s < SS; s += 64) {
            if (mrow[s] != 0) {
                ++cnt;
                const int tag  = trow[s];
                const int prev = (s == 0) ? START_TAG : trow[s - 1];
                acc += frow[(size_t)s * TT + tag] + trans[prev * TT + tag];
            }
        }
        #pragma unroll
        for (int off = 32; off; off >>= 1) {
            acc += __shfl_xor(acc, off);
            cnt += __shfl_xor(cnt, off);
        }
        if (lane == 0) {
            const int end_id = trow[cnt - 1];
            atomicAdd(out, -(acc + trans[end_id * TT + STOP_TAG]));
        }
    }
}

__global__ void zero_out(float* out) { out[0] = 0.f; }

extern "C" void kernel_launch(void* const* d_in, const int* in_sizes, int n_in,
                              void* d_out, int out_size, void* d_ws, size_t ws_size,
                              hipStream_t stream) {
    const float* feats = (const float*)d_in[0];   // (B,S,T) f32
    const int*   mask  = (const int*)d_in[1];     // (B,S)   int (0/1)
    const int*   tags  = (const int*)d_in[2];     // (B,S)   int
    const float* trans = (const float*)d_in[3];   // (T,T)   f32
    float* out = (float*)d_out;

    zero_out<<<1, 1, 0, stream>>>(out);
    crf_main<<<BB, 128, 0, stream>>>(feats, mask, tags, trans, out);
}